// Round 16
// baseline (223.357 us; speedup 1.0000x reference)
//
#include <hip/hip_runtime.h>
#include <hip/hip_bf16.h>
#include <math.h>

#define N_PTS 16384
#define KNN 8

#define DT_BF16 1
#define DT_FP32 2

// Workspace layout:
//   flag : int          @ 0
//   idx  : int  [N*9]   @ 64        -> 589,824 B
//   x1   : f32  [N*64]  @ 589,888   -> 4,194,304 B
// Grid-KNN scratch lives INSIDE the x1 region (dead before conv1 writes x1):
//   sat      : int [110592]  @ x1+0
//   start    : int [110593]  @ x1+442368
//   cursor   : int [110592]  @ x1+884800
//   pid      : int [16384]   @ x1+1327168
//   pts4     : f4  [16384]   @ x1+1392704
//   rowtot   : int [2304]    @ x1+1654848
//   rowstart : int [2304]    @ x1+1664064
//   xpre     : int [110592]  @ x1+1673280  (end 2,115,648 <= 4,194,304)
#define WS_FLAG_OFF 0
#define WS_IDX_OFF  64
#define WS_X1_OFF   589888
#define WS_NEEDED   4784192

#define WS_SAT_OFF      (WS_X1_OFF)
#define WS_START_OFF    (WS_X1_OFF + 442368)
#define WS_CURSOR_OFF   (WS_X1_OFF + 884800)
#define WS_PID_OFF      (WS_X1_OFF + 1327168)
#define WS_PTS_OFF      (WS_X1_OFF + 1392704)
#define WS_ROWTOT_OFF   (WS_X1_OFF + 1654848)
#define WS_ROWSTART_OFF (WS_X1_OFF + 1664064)
#define WS_XPRE_OFF     (WS_X1_OFF + 1673280)

#define GRID_R   48
#define NROWS2D  (GRID_R * GRID_R)
#define NCELLS   (GRID_R * GRID_R * GRID_R)
#define GLO      -4.5f
#define CELL_E   0.1875f
#define CELL_INV 5.3333335f
#define NBR_MIN  40
#define NBR_LO   9
#define M_CAP    1024
#define R_DIRECT 96

#define SENT_KEY 0xFF800000FFFFFFFFull

__device__ __forceinline__ float bf2f(__hip_bfloat16 v) { return __bfloat162float(v); }

__device__ __forceinline__ float ldf(const float* p, int i) { return p[i]; }
__device__ __forceinline__ float ldf(const __hip_bfloat16* p, int i) { return bf2f(p[i]); }
__device__ __forceinline__ void stf(float* p, int i, float v) { p[i] = v; }
__device__ __forceinline__ void stf(__hip_bfloat16* p, int i, float v) { p[i] = __float2bfloat16(v); }

__device__ __forceinline__ int clamp_idx(int j) {
    return ((unsigned)j < (unsigned)N_PTS) ? j : 0;
}

__device__ __forceinline__ int cell_of(float v) {
    int c = (int)((v - GLO) * CELL_INV);
    return min(max(c, 0), GRID_R - 1);
}

__device__ __forceinline__ unsigned fkey(float d) {
    unsigned b = __float_as_uint(d);
    return b ^ ((unsigned)((int)b >> 31) | 0x80000000u);
}
__device__ __forceinline__ float fkey_inv(unsigned k) {
    unsigned b = (k & 0x80000000u) ? (k ^ 0x80000000u) : ~k;
    return __uint_as_float(b);
}

__device__ __forceinline__ int get_dt(const int* flag) {
    return (flag[0] > 16) ? DT_FP32 : DT_BF16;
}

// ---------------------------------------------------------------------------
__global__ __launch_bounds__(256) void zero_kernel(int* __restrict__ cnt, int* __restrict__ flag) {
    const int e = blockIdx.x * 256 + threadIdx.x;
    cnt[e] = 0;
    if (e == 0) flag[0] = 0;
}

__global__ __launch_bounds__(256) void sniff_kernel(const unsigned short* __restrict__ posu,
                                                    int* __restrict__ flag) {
    __shared__ int red[256];
    int local = 0;
    for (int e = blockIdx.x * 256 + threadIdx.x; e < 3 * N_PTS; e += 64 * 256) {
        const float v = __uint_as_float(((unsigned)posu[e]) << 16);
        if (!(fabsf(v) <= 64.0f)) local++;
    }
    red[threadIdx.x] = local;
    __syncthreads();
    for (int s = 128; s > 0; s >>= 1) {
        if (threadIdx.x < s) red[threadIdx.x] += red[threadIdx.x + s];
        __syncthreads();
    }
    if (threadIdx.x == 0 && red[0] > 0) atomicAdd(flag, red[0]);
}

// ---------------------------------------------------------------------------
template <typename T>
__device__ __forceinline__ void count_body(const T* __restrict__ pos, int* __restrict__ cnt) {
    const int i = blockIdx.x * 256 + threadIdx.x;
    const float x = ldf(pos, 3 * i + 0);
    const float y = ldf(pos, 3 * i + 1);
    const float z = ldf(pos, 3 * i + 2);
    const int c = (cell_of(z) * GRID_R + cell_of(y)) * GRID_R + cell_of(x);
    atomicAdd(&cnt[c], 1);
}

__global__ __launch_bounds__(256) void grid_count_kernel(const void* __restrict__ pos,
                                                         const int* __restrict__ flag,
                                                         int* __restrict__ cnt) {
    if (get_dt(flag) == DT_BF16) count_body<__hip_bfloat16>((const __hip_bfloat16*)pos, cnt);
    else                         count_body<float>((const float*)pos, cnt);
}

__global__ __launch_bounds__(256) void rowscan_kernel(int* __restrict__ sat,
                                                      int* __restrict__ xpre,
                                                      int* __restrict__ rowtot) {
    const int t = blockIdx.x * 256 + threadIdx.x;
    const int rb = t * GRID_R;
    int acc = 0;
    for (int x = 0; x < GRID_R; ++x) {
        acc += sat[rb + x];
        sat[rb + x]  = acc;
        xpre[rb + x] = acc;
    }
    rowtot[t] = acc;
}

__global__ __launch_bounds__(256) void rowoffset_kernel(const int* __restrict__ rowtot,
                                                        int* __restrict__ rowstart) {
    __shared__ int part[256];
    const int t = threadIdx.x;
    int loc[9]; int s = 0;
#pragma unroll
    for (int k = 0; k < 9; ++k) { loc[k] = rowtot[t * 9 + k]; s += loc[k]; }
    part[t] = s;
    __syncthreads();
    for (int off = 1; off < 256; off <<= 1) {
        int v = (t >= off) ? part[t - off] : 0;
        __syncthreads();
        part[t] += v;
        __syncthreads();
    }
    int run = (t == 0) ? 0 : part[t - 1];
#pragma unroll
    for (int k = 0; k < 9; ++k) { rowstart[t * 9 + k] = run; run += loc[k]; }
}

__global__ __launch_bounds__(256) void cellsaty_kernel(const int* __restrict__ xpre,
                                                       const int* __restrict__ rowstart,
                                                       int* __restrict__ cstart,
                                                       int* __restrict__ cursor,
                                                       int* __restrict__ sat) {
    const int t = blockIdx.x * 256 + threadIdx.x;
    const int rb = t * GRID_R;
    const int base = rowstart[t];
    int prev = 0;
    for (int x = 0; x < GRID_R; ++x) {
        const int v = base + prev;
        cstart[rb + x] = v;
        cursor[rb + x] = v;
        prev = xpre[rb + x];
    }
    if (t == NROWS2D - 1) cstart[NCELLS] = base + prev;
    const int z = t / GRID_R, x = t - z * GRID_R;
    const int b2 = z * NROWS2D + x;
    int run = 0;
#pragma unroll
    for (int y = 0; y < GRID_R; ++y) {
        run += sat[b2 + y * GRID_R];
        sat[b2 + y * GRID_R] = run;
    }
}

template <typename T>
__device__ __forceinline__ void scatter_body(const T* __restrict__ pos, int i,
                                             int* __restrict__ cursor,
                                             float4* __restrict__ pts4, int* __restrict__ pid) {
    const float x = ldf(pos, 3 * i + 0);
    const float y = ldf(pos, 3 * i + 1);
    const float z = ldf(pos, 3 * i + 2);
    const int c = (cell_of(z) * GRID_R + cell_of(y)) * GRID_R + cell_of(x);
    const int slot = atomicAdd(&cursor[c], 1);
    const float sq = fmaf(x, x, fmaf(y, y, z * z));
    pts4[slot] = make_float4(-2.0f * x, -2.0f * y, -2.0f * z, sq);
    pid[slot] = i;
}

__global__ __launch_bounds__(256) void satzscatter_kernel(const void* __restrict__ pos,
                                                          const int* __restrict__ flag,
                                                          int* __restrict__ sat,
                                                          int* __restrict__ cursor,
                                                          float4* __restrict__ pts4,
                                                          int* __restrict__ pid) {
    if (blockIdx.x < 9) {
        const int t = blockIdx.x * 256 + threadIdx.x;
        int run = 0;
#pragma unroll
        for (int z = 0; z < GRID_R; ++z) {
            run += sat[t + z * NROWS2D];
            sat[t + z * NROWS2D] = run;
        }
    } else {
        const int i = (blockIdx.x - 9) * 256 + threadIdx.x;
        if (get_dt(flag) == DT_BF16) scatter_body<__hip_bfloat16>((const __hip_bfloat16*)pos, i, cursor, pts4, pid);
        else                         scatter_body<float>((const float*)pos, i, cursor, pts4, pid);
    }
}

// ---------------------------------------------------------------------------
// KNN (converged structure, unchanged from r15): 128-thread blocks, SAT
// probe, hybrid staged/direct window scan, u64-key bitonic merge.
// ---------------------------------------------------------------------------
__device__ __forceinline__ int sat_at(const int* __restrict__ sat, int x, int y, int z) {
    if (x < 0 || y < 0 || z < 0) return 0;
    return sat[(z * GRID_R + y) * GRID_R + x];
}

__device__ __forceinline__ int boxcount(const int* __restrict__ sat,
                                        int x0, int x1, int y0, int y1, int z0, int z1) {
    return sat_at(sat, x1, y1, z1) - sat_at(sat, x0 - 1, y1, z1)
         - sat_at(sat, x1, y0 - 1, z1) - sat_at(sat, x1, y1, z0 - 1)
         + sat_at(sat, x0 - 1, y0 - 1, z1) + sat_at(sat, x0 - 1, y1, z0 - 1)
         + sat_at(sat, x1, y0 - 1, z0 - 1) - sat_at(sat, x0 - 1, y0 - 1, z0 - 1);
}

template <typename T>
__device__ void knn_body(const T* __restrict__ pos,
                         const int* __restrict__ cstart, const int* __restrict__ sat,
                         const float4* __restrict__ pts4, const int* __restrict__ pid,
                         int* __restrict__ idx_out,
                         int* __restrict__ rs, int* __restrict__ epf) {
    const int tid  = threadIdx.x;
    const int lane = tid & 31;
    const int i    = blockIdx.x * 4 + (tid >> 5);

    const float pix = ldf(pos, 3 * i + 0);
    const float piy = ldf(pos, 3 * i + 1);
    const float piz = ldf(pos, 3 * i + 2);
    const float sqi = fmaf(pix, pix, fmaf(piy, piy, piz * piz));
    const int cx = cell_of(pix), cy = cell_of(piy), cz = cell_of(piz);

    unsigned long long bk[KNN];
#pragma unroll
    for (int q = 0; q < KNN; ++q) bk[q] = SENT_KEY;
    unsigned long long tk = SENT_KEY;

    auto do_insert = [&](unsigned long long ck) {
#pragma unroll
        for (int q = 0; q < KNN; ++q) {
            const unsigned long long old = bk[q];
            const bool ins = ck < old;
            bk[q] = ins ? ck : old;
            ck    = ins ? old : ck;
        }
        tk = (bk[KNN - 1] < tk) ? bk[KNN - 1] : tk;
    };

    auto clip_row = [&](int ycell, int zcell, float clip2, bool doclip,
                        int x0, int x1, int& cxa, int& cxb) -> bool {
        cxa = x0; cxb = x1;
        if (doclip) {
            const float ylo = GLO + (float)ycell * CELL_E;
            const float zlo = GLO + (float)zcell * CELL_E;
            const float dy = fmaxf(0.0f, fmaxf(ylo - piy, piy - (ylo + CELL_E)));
            const float dz = fmaxf(0.0f, fmaxf(zlo - piz, piz - (zlo + CELL_E)));
            const float rad2 = clip2 - dy * dy - dz * dz;
            if (rad2 <= 0.0f) return false;
            const float hr = sqrtf(rad2) + 1e-4f;
            cxa = max(x0, (int)floorf((pix - hr - GLO) * CELL_INV));
            cxb = min(x1, (int)floorf((pix + hr - GLO) * CELL_INV));
        }
        return cxa <= cxb;
    };

    auto cand_key = [&](int si) -> unsigned long long {
        const float4 cq = pts4[si];
        const int pj = pid[si];
        const float d = fmaf(cq.x, pix, fmaf(cq.y, piy, fmaf(cq.z, piz, cq.w)));
        if (pj == i) return SENT_KEY;
        return ((unsigned long long)fkey(d) << 32) | (unsigned)pj;
    };

    auto scan_win = [&](int rr, float clipR) {
        const int x0 = max(cx - rr, 0), x1 = min(cx + rr, GRID_R - 1);
        const int y0 = max(cy - rr, 0), y1 = min(cy + rr, GRID_R - 1);
        const int z0 = max(cz - rr, 0), z1 = min(cz + rr, GRID_R - 1);
        const int ny = y1 - y0 + 1;
        const int nz = z1 - z0 + 1;
        const int R  = ny * nz;
        const float clip2 = clipR * clipR;
        const bool doclip = (clipR < 1e30f);

        if (R > R_DIRECT) {
            for (int t0 = lane; t0 < R; t0 += 128) {
                int s0v[4], s1v[4];
#pragma unroll
                for (int k = 0; k < 4; ++k) {
                    const int row = t0 + (k << 5);
                    s0v[k] = 0; s1v[k] = 0;
                    if (row < R) {
                        const int iz = row / ny;
                        const int iy = row - iz * ny;
                        int cxa, cxb;
                        if (clip_row(y0 + iy, z0 + iz, clip2, doclip, x0, x1, cxa, cxb)) {
                            const int c0 = ((z0 + iz) * GRID_R + (y0 + iy)) * GRID_R + cxa;
                            s0v[k] = cstart[c0];
                            s1v[k] = cstart[c0 + (cxb - cxa) + 1];
                        }
                    }
                }
#pragma unroll
                for (int k = 0; k < 4; ++k) {
                    for (int si = s0v[k]; si < s1v[k]; ++si) {
                        const unsigned long long ck = cand_key(si);
                        if (ck <= tk) do_insert(ck);
                    }
                }
            }
            return;
        }

        for (int cb = 0; cb < R; cb += 32) {
            const int lr = cb + lane;
            int cnt_r = 0, st_r = 0;
            if (lr < R) {
                const int izq = lr / ny;
                const int iyq = lr - izq * ny;
                int cxa, cxb;
                if (clip_row(y0 + iyq, z0 + izq, clip2, doclip, x0, x1, cxa, cxb)) {
                    const int c0 = ((z0 + izq) * GRID_R + (y0 + iyq)) * GRID_R + cxa;
                    st_r  = cstart[c0];
                    cnt_r = cstart[c0 + (cxb - cxa) + 1] - st_r;
                }
            }
            int pv = cnt_r;
#pragma unroll
            for (int s = 1; s < 32; s <<= 1) {
                const int u = __shfl_up(pv, s, 32);
                if (lane >= s) pv += u;
            }
            const int Mtot = __shfl(pv, 31, 32);
            asm volatile("s_waitcnt lgkmcnt(0)" ::: "memory");
            rs[lane]  = st_r;
            epf[lane] = (lr < R) ? (pv - cnt_r) : 0x7fffffff;
            asm volatile("s_waitcnt lgkmcnt(0)" ::: "memory");
            for (int tb = 0; tb < Mtot; tb += 128) {
                unsigned long long ck[4];
#pragma unroll
                for (int k = 0; k < 4; ++k) {
                    const int t = tb + (k << 5) + lane;
                    ck[k] = SENT_KEY;
                    if (t < Mtot) {
                        int p = 0;
#pragma unroll
                        for (int st = 16; st >= 1; st >>= 1)
                            if (epf[p + st] <= t) p += st;
                        ck[k] = cand_key(rs[p] + (t - epf[p]));
                    }
                }
#pragma unroll
                for (int k = 0; k < 4; ++k)
                    if (ck[k] <= tk) do_insert(ck[k]);
            }
        }
    };

    auto merge_all = [&]() {
#pragma unroll
        for (int s = 1; s < 32; s <<= 1) {
            unsigned long long m[KNN];
#pragma unroll
            for (int q = 0; q < KNN; ++q) {
                const unsigned long long o = __shfl_xor(bk[KNN - 1 - q], s, 32);
                m[q] = (bk[q] < o) ? bk[q] : o;
            }
#pragma unroll
            for (int d = 4; d >= 1; d >>= 1) {
#pragma unroll
                for (int q = 0; q < KNN; ++q) {
                    if (!(q & d)) {
                        const unsigned long long a = m[q], b = m[q + d];
                        const bool sw = b < a;
                        m[q]     = sw ? b : a;
                        m[q + d] = sw ? a : b;
                    }
                }
            }
#pragma unroll
            for (int q = 0; q < KNN; ++q) bk[q] = m[q];
        }
        tk = bk[KNN - 1];
    };

    int r;
    {
        const int rl = lane + 1;
        const int bx0 = max(cx - rl, 0), bx1 = min(cx + rl, GRID_R - 1);
        const int by0 = max(cy - rl, 0), by1 = min(cy + rl, GRID_R - 1);
        const int bz0 = max(cz - rl, 0), bz1 = min(cz + rl, GRID_R - 1);
        const int cntl = boxcount(sat, bx0, bx1, by0, by1, bz0, bz1);
        const unsigned long long m9  = __ballot(cntl >= NBR_LO);
        const unsigned long long m26 = __ballot(cntl >= NBR_MIN);
        const unsigned sh  = (unsigned)(tid & 32);
        const unsigned mh9  = (unsigned)(m9  >> sh);
        const unsigned mh26 = (unsigned)(m26 >> sh);
        const int r9  = mh9  ? (int)__ffs(mh9)  : 32;
        const int r26 = mh26 ? (int)__ffs(mh26) : 32;
        const int cnt26 = __shfl(cntl, r26 - 1, 32);
        r = (cnt26 <= M_CAP) ? r26 : r9;
    }

    scan_win(r, INFINITY);

    {
        float mg = INFINITY;
        bool full = true;
        if (cx - r > 0)          { mg = fminf(mg, pix - (GLO + (float)(cx - r) * CELL_E));     full = false; }
        if (cx + r < GRID_R - 1) { mg = fminf(mg, (GLO + (float)(cx + r + 1) * CELL_E) - pix); full = false; }
        if (cy - r > 0)          { mg = fminf(mg, piy - (GLO + (float)(cy - r) * CELL_E));     full = false; }
        if (cy + r < GRID_R - 1) { mg = fminf(mg, (GLO + (float)(cy + r + 1) * CELL_E) - piy); full = false; }
        if (cz - r > 0)          { mg = fminf(mg, piz - (GLO + (float)(cz - r) * CELL_E));     full = false; }
        if (cz + r < GRID_R - 1) { mg = fminf(mg, (GLO + (float)(cz + r + 1) * CELL_E) - piz); full = false; }

        merge_all();
        bool done = full;
        const unsigned long long d8key = bk[KNN - 1];
        const float d8 = fkey_inv((unsigned)(d8key >> 32));
        if (!full) {
            const float mge  = mg - 1e-5f;
            const float need = mge * mge - sqi;
            done = (d8 < need);
        }

        if (!done) {
            float s2 = sqrtf(fmaxf(d8 + sqi, 0.0f)) + 1e-4f;
            s2 = fminf(s2, 9.0f);
            auto dneed = [&](float frac, int clip) -> int {
                int nd = (int)ceilf((s2 - frac) * CELL_INV);
                nd = max(nd, 0);
                return min(nd, clip);
            };
            const float fxm = pix - (GLO + (float)cx * CELL_E);
            const float fxp = (GLO + (float)(cx + 1) * CELL_E) - pix;
            const float fym = piy - (GLO + (float)cy * CELL_E);
            const float fyp = (GLO + (float)(cy + 1) * CELL_E) - piy;
            const float fzm = piz - (GLO + (float)cz * CELL_E);
            const float fzp = (GLO + (float)(cz + 1) * CELL_E) - piz;
            int r2 = r + 1;
            r2 = max(r2, dneed(fxm, cx));
            r2 = max(r2, dneed(fxp, GRID_R - 1 - cx));
            r2 = max(r2, dneed(fym, cy));
            r2 = max(r2, dneed(fyp, GRID_R - 1 - cy));
            r2 = max(r2, dneed(fzm, cz));
            r2 = max(r2, dneed(fzp, GRID_R - 1 - cz));
            r2 = min(r2, GRID_R);

#pragma unroll
            for (int q = 0; q < KNN; ++q) bk[q] = SENT_KEY;
            tk = d8key;
            scan_win(r2, (d8 < INFINITY) ? s2 : INFINITY);
            merge_all();
        }
    }

    if (lane == 0) {
#pragma unroll
        for (int k = 0; k < KNN; ++k) idx_out[i * 9 + k] = clamp_idx((int)(unsigned)bk[k]);
        idx_out[i * 9 + 8] = i;
    }
}

__global__ __launch_bounds__(128) void knn_grid_kernel(const void* __restrict__ pos,
                                                       const int* __restrict__ flag,
                                                       const int* __restrict__ cstart,
                                                       const int* __restrict__ sat,
                                                       const float4* __restrict__ pts4,
                                                       const int* __restrict__ pid,
                                                       int* __restrict__ idx_out) {
    __shared__ int rs[4][32];
    __shared__ int epf[4][32];
    const int sg = threadIdx.x >> 5;
    if (get_dt(flag) == DT_BF16)
        knn_body<__hip_bfloat16>((const __hip_bfloat16*)pos, cstart, sat, pts4, pid, idx_out,
                                 rs[sg], epf[sg]);
    else
        knn_body<float>((const float*)pos, cstart, sat, pts4, pid, idx_out, rs[sg], epf[sg]);
}

// ---------------------------------------------------------------------------
// conv1+zw FUSED (unchanged from r15).
// ---------------------------------------------------------------------------
struct Conv1Smem {
    alignas(16) float big[4288];
    alignas(16) float wsum[3 * 32];
    alignas(16) float wbot[3 * 32];
    alignas(16) float posn[4][9][3];
    alignas(16) float xr[4][64];
    float bA[32];
    float bB[64];
    float bA2[64];
};

template <typename T>
__device__ void conv1_body(const T* __restrict__ pos, const int* __restrict__ idx,
                           const T* __restrict__ W1a, const T* __restrict__ b1a,
                           const T* __restrict__ W1b, const T* __restrict__ b1b,
                           const T* __restrict__ W2a, const T* __restrict__ b2a,
                           float* __restrict__ x1, Conv1Smem& s) {
    const int tid = threadIdx.x;
    float* wB  = s.big;
    float* h1s = s.big + 2048;

    for (int e = tid; e < 96; e += 256) {
        const float bot = ldf(W1a, 96 + e);
        s.wsum[e] = ldf(W1a, e) + bot;
        s.wbot[e] = bot;
    }
    if (tid < 32) s.bA[tid] = ldf(b1a, tid);
    for (int e = tid; e < 2048; e += 256) wB[e] = ldf(W1b, e);
    if (tid < 64) s.bB[tid] = ldf(b1b, tid);
    if (tid < 64) s.bA2[tid] = ldf(b2a, tid);

    const int tl   = tid >> 6;
    const int lane = tid & 63;
    const int i    = blockIdx.x * 4 + tl;

    if (lane < 27) {
        const int n = lane / 3, c = lane % 3;
        const int j = clamp_idx(idx[i * 9 + n]);
        s.posn[tl][n][c] = ldf(pos, 3 * j + c);
    }
    const float pi0 = ldf(pos, 3 * i + 0);
    const float pi1 = ldf(pos, 3 * i + 1);
    const float pi2 = ldf(pos, 3 * i + 2);
    __syncthreads();

    for (int e = lane; e < 288; e += 64) {
        const int n = e >> 5, k = e & 31;
        float b = fmaf(pi0, s.wbot[k], fmaf(pi1, s.wbot[32 + k], pi2 * s.wbot[64 + k]));
        float v = s.bA[k] - b;
        v = fmaf(s.posn[tl][n][0], s.wsum[k], v);
        v = fmaf(s.posn[tl][n][1], s.wsum[32 + k], v);
        v = fmaf(s.posn[tl][n][2], s.wsum[64 + k], v);
        h1s[tl * 288 + n * 32 + k] = fmaxf(v, 0.0f);
    }
    __syncthreads();

    float acc[9];
#pragma unroll
    for (int n = 0; n < 9; ++n) acc[n] = 0.0f;
#pragma unroll
    for (int kt = 0; kt < 32; kt += 8) {
        float w0 = wB[(kt + 0) * 64 + lane];
        float w1 = wB[(kt + 1) * 64 + lane];
        float w2 = wB[(kt + 2) * 64 + lane];
        float w3 = wB[(kt + 3) * 64 + lane];
        float w4 = wB[(kt + 4) * 64 + lane];
        float w5 = wB[(kt + 5) * 64 + lane];
        float w6 = wB[(kt + 6) * 64 + lane];
        float w7 = wB[(kt + 7) * 64 + lane];
#pragma unroll
        for (int n = 0; n < 9; ++n) {
            const float4 ha = *(const float4*)&h1s[tl * 288 + n * 32 + kt];
            const float4 hb = *(const float4*)&h1s[tl * 288 + n * 32 + kt + 4];
            float a = acc[n];
            a = fmaf(ha.x, w0, a); a = fmaf(ha.y, w1, a);
            a = fmaf(ha.z, w2, a); a = fmaf(ha.w, w3, a);
            a = fmaf(hb.x, w4, a); a = fmaf(hb.y, w5, a);
            a = fmaf(hb.z, w6, a); a = fmaf(hb.w, w7, a);
            acc[n] = a;
        }
    }
    float m = acc[0];
#pragma unroll
    for (int n = 1; n < 9; ++n) m = fmaxf(m, acc[n]);
    const float xv = fmaxf(m + s.bB[lane], 0.0f);

    __syncthreads();
    s.xr[tl][lane] = xv;
    for (int e = tid; e < 4288; e += 256) s.big[e] = ldf(W2a, e);
    __syncthreads();

    float a0 = s.bA2[lane], a1 = 0.0f, a2 = 0.0f, a3 = 0.0f;
#pragma unroll
    for (int c = 0; c < 64; c += 4) {
        a0 = fmaf(s.xr[tl][c + 0], s.big[(c + 0) * 64 + lane], a0);
        a1 = fmaf(s.xr[tl][c + 1], s.big[(c + 1) * 64 + lane], a1);
        a2 = fmaf(s.xr[tl][c + 2], s.big[(c + 2) * 64 + lane], a2);
        a3 = fmaf(s.xr[tl][c + 3], s.big[(c + 3) * 64 + lane], a3);
    }
    float a = (a0 + a1) + (a2 + a3);
    a = fmaf(pi0, s.big[64 * 64 + lane], a);
    a = fmaf(pi1, s.big[65 * 64 + lane], a);
    a = fmaf(pi2, s.big[66 * 64 + lane], a);
    x1[i * 64 + lane] = a;
}

__global__ __launch_bounds__(256) void conv1zw_kernel(const void* __restrict__ pos,
                                                      const int* __restrict__ flag,
                                                      const int* __restrict__ idx,
                                                      const void* __restrict__ W1a,
                                                      const void* __restrict__ b1a,
                                                      const void* __restrict__ W1b,
                                                      const void* __restrict__ b1b,
                                                      const void* __restrict__ W2a,
                                                      const void* __restrict__ b2a,
                                                      float* __restrict__ x1) {
    __shared__ Conv1Smem s;
    if (get_dt(flag) == DT_BF16)
        conv1_body<__hip_bfloat16>((const __hip_bfloat16*)pos, idx,
            (const __hip_bfloat16*)W1a, (const __hip_bfloat16*)b1a,
            (const __hip_bfloat16*)W1b, (const __hip_bfloat16*)b1b,
            (const __hip_bfloat16*)W2a, (const __hip_bfloat16*)b2a, x1, s);
    else
        conv1_body<float>((const float*)pos, idx, (const float*)W1a, (const float*)b1a,
            (const float*)W1b, (const float*)b1b,
            (const float*)W2a, (const float*)b2a, x1, s);
}

// ---------------------------------------------------------------------------
// conv2+head v12: 8 targets/block (grid 2048). Each thread applies its named
// weight registers to TWO targets (tl and tl+4) — halves the per-target
// W2b load+convert+addressing cost that r15 counters showed eating ~half of
// conv2's VALU issue (53us vs ~15us pure-fma floor, VALUBusy 63%). LDS ~26KB
// -> 6 blocks/CU. Identical arithmetic per target.
// ---------------------------------------------------------------------------
struct Conv2Smem {
    alignas(16) float h1s[8][9 * 64];
    alignas(16) float row[8][128];
    alignas(16) float wbot[3 * 64];
    alignas(16) float wc[640];
    float bcs[5];
    float sv[8][5];
    int   nb[8][9];
};

template <typename T>
__device__ void conv2_body(const T* __restrict__ pos, const int* __restrict__ idx,
                           const float* __restrict__ zw,
                           const T* __restrict__ W2a, const T* __restrict__ W2b,
                           const T* __restrict__ b2b, const T* __restrict__ Wc,
                           const T* __restrict__ bc, T* __restrict__ out, Conv2Smem& s) {
    const int tid  = threadIdx.x;
    const int tl   = tid >> 6;         // target slot A (0..3); slot B = tl+4
    const int lane = tid & 63;
    const int iA   = blockIdx.x * 8 + tl;
    const int iB   = iA + 4;

    for (int e = tid; e < 192; e += 256) s.wbot[e] = ldf(W2a, 4096 + e);
    for (int e = tid; e < 640; e += 256) s.wc[e] = ldf(Wc, e);
    if (tid < 5) s.bcs[tid] = ldf(bc, tid);

    if (lane < 9) {
        s.nb[tl][lane]     = clamp_idx(idx[iA * 9 + lane]);
        s.nb[tl + 4][lane] = clamp_idx(idx[iB * 9 + lane]);
    }
    const float pA0 = ldf(pos, 3 * iA + 0);
    const float pA1 = ldf(pos, 3 * iA + 1);
    const float pA2 = ldf(pos, 3 * iA + 2);
    const float pB0 = ldf(pos, 3 * iB + 0);
    const float pB1 = ldf(pos, 3 * iB + 1);
    const float pB2 = ldf(pos, 3 * iB + 2);
    __syncthreads();

    // h1 = relu(zw[j] - vi) for both targets (18 coalesced row-gathers)
    {
        const float wb0 = s.wbot[lane], wb1 = s.wbot[64 + lane], wb2 = s.wbot[128 + lane];
        const float viA = fmaf(pA0, wb0, fmaf(pA1, wb1, pA2 * wb2));
        const float viB = fmaf(pB0, wb0, fmaf(pB1, wb1, pB2 * wb2));
#pragma unroll
        for (int n = 0; n < 9; ++n) {
            const int jA = s.nb[tl][n];
            const int jB = s.nb[tl + 4][n];
            s.h1s[tl][n * 64 + lane]     = fmaxf(zw[jA * 64 + lane] - viA, 0.0f);
            s.h1s[tl + 4][n * 64 + lane] = fmaxf(zw[jB * 64 + lane] - viB, 0.0f);
        }
    }
    __syncthreads();

    // wB: weight regs shared across 2 targets; 36 accumulators
    float aA0[9], aA1[9], aB0[9], aB1[9];
#pragma unroll
    for (int n = 0; n < 9; ++n) { aA0[n] = 0.0f; aA1[n] = 0.0f; aB0[n] = 0.0f; aB1[n] = 0.0f; }
#pragma unroll
    for (int kt = 0; kt < 64; kt += 4) {
        const float wa0 = ldf(W2b, (kt + 0) * 128 + lane);
        const float wa1 = ldf(W2b, (kt + 1) * 128 + lane);
        const float wa2 = ldf(W2b, (kt + 2) * 128 + lane);
        const float wa3 = ldf(W2b, (kt + 3) * 128 + lane);
        const float wb0 = ldf(W2b, (kt + 0) * 128 + lane + 64);
        const float wb1 = ldf(W2b, (kt + 1) * 128 + lane + 64);
        const float wb2 = ldf(W2b, (kt + 2) * 128 + lane + 64);
        const float wb3 = ldf(W2b, (kt + 3) * 128 + lane + 64);
#pragma unroll
        for (int n = 0; n < 9; ++n) {
            const float4 hA = *(const float4*)&s.h1s[tl][n * 64 + kt];
            const float4 hB = *(const float4*)&s.h1s[tl + 4][n * 64 + kt];
            float x0 = aA0[n], x1v = aA1[n], y0 = aB0[n], y1 = aB1[n];
            x0 = fmaf(hA.x, wa0, x0); x0 = fmaf(hA.y, wa1, x0);
            x0 = fmaf(hA.z, wa2, x0); x0 = fmaf(hA.w, wa3, x0);
            x1v = fmaf(hA.x, wb0, x1v); x1v = fmaf(hA.y, wb1, x1v);
            x1v = fmaf(hA.z, wb2, x1v); x1v = fmaf(hA.w, wb3, x1v);
            y0 = fmaf(hB.x, wa0, y0); y0 = fmaf(hB.y, wa1, y0);
            y0 = fmaf(hB.z, wa2, y0); y0 = fmaf(hB.w, wa3, y0);
            y1 = fmaf(hB.x, wb0, y1); y1 = fmaf(hB.y, wb1, y1);
            y1 = fmaf(hB.z, wb2, y1); y1 = fmaf(hB.w, wb3, y1);
            aA0[n] = x0; aA1[n] = x1v; aB0[n] = y0; aB1[n] = y1;
        }
    }
    float mA0 = aA0[0], mA1 = aA1[0], mB0 = aB0[0], mB1 = aB1[0];
#pragma unroll
    for (int n = 1; n < 9; ++n) {
        mA0 = fmaxf(mA0, aA0[n]); mA1 = fmaxf(mA1, aA1[n]);
        mB0 = fmaxf(mB0, aB0[n]); mB1 = fmaxf(mB1, aB1[n]);
    }
    const float b0 = ldf(b2b, lane), b1 = ldf(b2b, lane + 64);
    s.row[tl][lane]          = fmaxf(mA0 + b0, 0.0f);
    s.row[tl][lane + 64]     = fmaxf(mA1 + b1, 0.0f);
    s.row[tl + 4][lane]      = fmaxf(mB0 + b0, 0.0f);
    s.row[tl + 4][lane + 64] = fmaxf(mB1 + b1, 0.0f);
    __syncthreads();

    // head + log_softmax (8 targets x 5 outputs = 40 threads)
    if (tid < 40) {
        const int tgt = tid / 5, o = tid % 5;
        float v = s.bcs[o];
        for (int k = 0; k < 128; ++k) v = fmaf(s.row[tgt][k], s.wc[k * 5 + o], v);
        s.sv[tgt][o] = v;
    }
    __syncthreads();
    if (tid < 40) {
        const int tgt = tid / 5, o = tid % 5;
        float m = s.sv[tgt][0];
#pragma unroll
        for (int q = 1; q < 5; ++q) m = fmaxf(m, s.sv[tgt][q]);
        float sum = 0.0f;
#pragma unroll
        for (int q = 0; q < 5; ++q) sum += expf(s.sv[tgt][q] - m);
        const float lse = m + logf(sum);
        stf(out, (blockIdx.x * 8 + tgt) * 5 + o, s.sv[tgt][o] - lse);
    }
}

__global__ __launch_bounds__(256) void conv2_head_kernel(const void* __restrict__ pos,
                                                         const int* __restrict__ flag,
                                                         const int* __restrict__ idx,
                                                         const float* __restrict__ zw,
                                                         const void* __restrict__ W2a,
                                                         const void* __restrict__ W2b,
                                                         const void* __restrict__ b2b,
                                                         const void* __restrict__ Wc,
                                                         const void* __restrict__ bc,
                                                         void* __restrict__ out) {
    __shared__ Conv2Smem s;
    if (get_dt(flag) == DT_BF16)
        conv2_body<__hip_bfloat16>((const __hip_bfloat16*)pos, idx, zw,
            (const __hip_bfloat16*)W2a, (const __hip_bfloat16*)W2b, (const __hip_bfloat16*)b2b,
            (const __hip_bfloat16*)Wc, (const __hip_bfloat16*)bc, (__hip_bfloat16*)out, s);
    else
        conv2_body<float>((const float*)pos, idx, zw, (const float*)W2a, (const float*)W2b,
            (const float*)b2b, (const float*)Wc, (const float*)bc, (float*)out, s);
}

// ---------------------------------------------------------------------------
extern "C" void kernel_launch(void* const* d_in, const int* in_sizes, int n_in,
                              void* d_out, int out_size, void* d_ws, size_t ws_size,
                              hipStream_t stream) {
    if (ws_size < (size_t)WS_NEEDED) return;

    char* ws = (char*)d_ws;
    int*    flag     = (int*)(ws + WS_FLAG_OFF);
    int*    idx      = (int*)(ws + WS_IDX_OFF);
    float*  x1       = (float*)(ws + WS_X1_OFF);
    int*    sat      = (int*)(ws + WS_SAT_OFF);
    int*    cstart   = (int*)(ws + WS_START_OFF);
    int*    cursor   = (int*)(ws + WS_CURSOR_OFF);
    int*    pid      = (int*)(ws + WS_PID_OFF);
    float4* pts4     = (float4*)(ws + WS_PTS_OFF);
    int*    rowtot   = (int*)(ws + WS_ROWTOT_OFF);
    int*    rowstart = (int*)(ws + WS_ROWSTART_OFF);
    int*    xpre     = (int*)(ws + WS_XPRE_OFF);

    zero_kernel<<<NCELLS / 256, 256, 0, stream>>>(sat, flag);
    sniff_kernel<<<64, 256, 0, stream>>>((const unsigned short*)d_in[0], flag);
    grid_count_kernel<<<N_PTS / 256, 256, 0, stream>>>(d_in[0], flag, sat);
    rowscan_kernel<<<NROWS2D / 256, 256, 0, stream>>>(sat, xpre, rowtot);
    rowoffset_kernel<<<1, 256, 0, stream>>>(rowtot, rowstart);
    cellsaty_kernel<<<NROWS2D / 256, 256, 0, stream>>>(xpre, rowstart, cstart, cursor, sat);
    satzscatter_kernel<<<9 + N_PTS / 256, 256, 0, stream>>>(d_in[0], flag, sat, cursor, pts4, pid);
    knn_grid_kernel<<<N_PTS / 4, 128, 0, stream>>>(d_in[0], flag, cstart, sat, pts4, pid, idx);
    conv1zw_kernel<<<N_PTS / 4, 256, 0, stream>>>(d_in[0], flag, idx,
        d_in[1], d_in[2], d_in[3], d_in[4], d_in[5], d_in[6], x1);
    conv2_head_kernel<<<N_PTS / 8, 256, 0, stream>>>(d_in[0], flag, idx, x1,
        d_in[5], d_in[7], d_in[8], d_in[9], d_in[10], d_out);
}

// Round 17
// 217.379 us; speedup vs baseline: 1.0275x; 1.0275x over previous
//
#include <hip/hip_runtime.h>
#include <hip/hip_bf16.h>
#include <math.h>

#define N_PTS 16384
#define KNN 8

#define DT_BF16 1
#define DT_FP32 2

// Workspace layout:
//   flag : int          @ 0
//   idx  : int  [N*9]   @ 64        -> 589,824 B
//   x1   : f32  [N*64]  @ 589,888   -> 4,194,304 B
// Grid-KNN scratch lives INSIDE the x1 region (dead before conv1 writes x1):
//   sat      : int [110592]  @ x1+0
//   start    : int [110593]  @ x1+442368
//   cursor   : int [110592]  @ x1+884800
//   pid      : int [16384]   @ x1+1327168
//   pts4     : f4  [16384]   @ x1+1392704
//   rowtot   : int [2304]    @ x1+1654848
//   rowstart : int [2304]    @ x1+1664064
//   xpre     : int [110592]  @ x1+1673280  (end 2,115,648 <= 4,194,304)
#define WS_FLAG_OFF 0
#define WS_IDX_OFF  64
#define WS_X1_OFF   589888
#define WS_NEEDED   4784192

#define WS_SAT_OFF      (WS_X1_OFF)
#define WS_START_OFF    (WS_X1_OFF + 442368)
#define WS_CURSOR_OFF   (WS_X1_OFF + 884800)
#define WS_PID_OFF      (WS_X1_OFF + 1327168)
#define WS_PTS_OFF      (WS_X1_OFF + 1392704)
#define WS_ROWTOT_OFF   (WS_X1_OFF + 1654848)
#define WS_ROWSTART_OFF (WS_X1_OFF + 1664064)
#define WS_XPRE_OFF     (WS_X1_OFF + 1673280)

#define GRID_R   48
#define NROWS2D  (GRID_R * GRID_R)
#define NCELLS   (GRID_R * GRID_R * GRID_R)
#define GLO      -4.5f
#define CELL_E   0.1875f
#define CELL_INV 5.3333335f
#define NBR_MIN  40
#define NBR_LO   9
#define M_CAP    1024
#define R_DIRECT 96

#define SENT_KEY 0xFF800000FFFFFFFFull

__device__ __forceinline__ float bf2f(__hip_bfloat16 v) { return __bfloat162float(v); }

__device__ __forceinline__ float ldf(const float* p, int i) { return p[i]; }
__device__ __forceinline__ float ldf(const __hip_bfloat16* p, int i) { return bf2f(p[i]); }
__device__ __forceinline__ void stf(float* p, int i, float v) { p[i] = v; }
__device__ __forceinline__ void stf(__hip_bfloat16* p, int i, float v) { p[i] = __float2bfloat16(v); }

__device__ __forceinline__ int clamp_idx(int j) {
    return ((unsigned)j < (unsigned)N_PTS) ? j : 0;
}

__device__ __forceinline__ int cell_of(float v) {
    int c = (int)((v - GLO) * CELL_INV);
    return min(max(c, 0), GRID_R - 1);
}

__device__ __forceinline__ unsigned fkey(float d) {
    unsigned b = __float_as_uint(d);
    return b ^ ((unsigned)((int)b >> 31) | 0x80000000u);
}
__device__ __forceinline__ float fkey_inv(unsigned k) {
    unsigned b = (k & 0x80000000u) ? (k ^ 0x80000000u) : ~k;
    return __uint_as_float(b);
}

__device__ __forceinline__ int get_dt(const int* flag) {
    return (flag[0] > 16) ? DT_FP32 : DT_BF16;
}

// ---------------------------------------------------------------------------
__global__ __launch_bounds__(256) void zero_kernel(int* __restrict__ cnt, int* __restrict__ flag) {
    const int e = blockIdx.x * 256 + threadIdx.x;
    cnt[e] = 0;
    if (e == 0) flag[0] = 0;
}

__global__ __launch_bounds__(256) void sniff_kernel(const unsigned short* __restrict__ posu,
                                                    int* __restrict__ flag) {
    __shared__ int red[256];
    int local = 0;
    for (int e = blockIdx.x * 256 + threadIdx.x; e < 3 * N_PTS; e += 64 * 256) {
        const float v = __uint_as_float(((unsigned)posu[e]) << 16);
        if (!(fabsf(v) <= 64.0f)) local++;
    }
    red[threadIdx.x] = local;
    __syncthreads();
    for (int s = 128; s > 0; s >>= 1) {
        if (threadIdx.x < s) red[threadIdx.x] += red[threadIdx.x + s];
        __syncthreads();
    }
    if (threadIdx.x == 0 && red[0] > 0) atomicAdd(flag, red[0]);
}

// ---------------------------------------------------------------------------
template <typename T>
__device__ __forceinline__ void count_body(const T* __restrict__ pos, int* __restrict__ cnt) {
    const int i = blockIdx.x * 256 + threadIdx.x;
    const float x = ldf(pos, 3 * i + 0);
    const float y = ldf(pos, 3 * i + 1);
    const float z = ldf(pos, 3 * i + 2);
    const int c = (cell_of(z) * GRID_R + cell_of(y)) * GRID_R + cell_of(x);
    atomicAdd(&cnt[c], 1);
}

__global__ __launch_bounds__(256) void grid_count_kernel(const void* __restrict__ pos,
                                                         const int* __restrict__ flag,
                                                         int* __restrict__ cnt) {
    if (get_dt(flag) == DT_BF16) count_body<__hip_bfloat16>((const __hip_bfloat16*)pos, cnt);
    else                         count_body<float>((const float*)pos, cnt);
}

__global__ __launch_bounds__(256) void rowscan_kernel(int* __restrict__ sat,
                                                      int* __restrict__ xpre,
                                                      int* __restrict__ rowtot) {
    const int t = blockIdx.x * 256 + threadIdx.x;
    const int rb = t * GRID_R;
    int acc = 0;
    for (int x = 0; x < GRID_R; ++x) {
        acc += sat[rb + x];
        sat[rb + x]  = acc;
        xpre[rb + x] = acc;
    }
    rowtot[t] = acc;
}

__global__ __launch_bounds__(256) void rowoffset_kernel(const int* __restrict__ rowtot,
                                                        int* __restrict__ rowstart) {
    __shared__ int part[256];
    const int t = threadIdx.x;
    int loc[9]; int s = 0;
#pragma unroll
    for (int k = 0; k < 9; ++k) { loc[k] = rowtot[t * 9 + k]; s += loc[k]; }
    part[t] = s;
    __syncthreads();
    for (int off = 1; off < 256; off <<= 1) {
        int v = (t >= off) ? part[t - off] : 0;
        __syncthreads();
        part[t] += v;
        __syncthreads();
    }
    int run = (t == 0) ? 0 : part[t - 1];
#pragma unroll
    for (int k = 0; k < 9; ++k) { rowstart[t * 9 + k] = run; run += loc[k]; }
}

__global__ __launch_bounds__(256) void cellsaty_kernel(const int* __restrict__ xpre,
                                                       const int* __restrict__ rowstart,
                                                       int* __restrict__ cstart,
                                                       int* __restrict__ cursor,
                                                       int* __restrict__ sat) {
    const int t = blockIdx.x * 256 + threadIdx.x;
    const int rb = t * GRID_R;
    const int base = rowstart[t];
    int prev = 0;
    for (int x = 0; x < GRID_R; ++x) {
        const int v = base + prev;
        cstart[rb + x] = v;
        cursor[rb + x] = v;
        prev = xpre[rb + x];
    }
    if (t == NROWS2D - 1) cstart[NCELLS] = base + prev;
    const int z = t / GRID_R, x = t - z * GRID_R;
    const int b2 = z * NROWS2D + x;
    int run = 0;
#pragma unroll
    for (int y = 0; y < GRID_R; ++y) {
        run += sat[b2 + y * GRID_R];
        sat[b2 + y * GRID_R] = run;
    }
}

template <typename T>
__device__ __forceinline__ void scatter_body(const T* __restrict__ pos, int i,
                                             int* __restrict__ cursor,
                                             float4* __restrict__ pts4, int* __restrict__ pid) {
    const float x = ldf(pos, 3 * i + 0);
    const float y = ldf(pos, 3 * i + 1);
    const float z = ldf(pos, 3 * i + 2);
    const int c = (cell_of(z) * GRID_R + cell_of(y)) * GRID_R + cell_of(x);
    const int slot = atomicAdd(&cursor[c], 1);
    const float sq = fmaf(x, x, fmaf(y, y, z * z));
    pts4[slot] = make_float4(-2.0f * x, -2.0f * y, -2.0f * z, sq);
    pid[slot] = i;
}

__global__ __launch_bounds__(256) void satzscatter_kernel(const void* __restrict__ pos,
                                                          const int* __restrict__ flag,
                                                          int* __restrict__ sat,
                                                          int* __restrict__ cursor,
                                                          float4* __restrict__ pts4,
                                                          int* __restrict__ pid) {
    if (blockIdx.x < 9) {
        const int t = blockIdx.x * 256 + threadIdx.x;
        int run = 0;
#pragma unroll
        for (int z = 0; z < GRID_R; ++z) {
            run += sat[t + z * NROWS2D];
            sat[t + z * NROWS2D] = run;
        }
    } else {
        const int i = (blockIdx.x - 9) * 256 + threadIdx.x;
        if (get_dt(flag) == DT_BF16) scatter_body<__hip_bfloat16>((const __hip_bfloat16*)pos, i, cursor, pts4, pid);
        else                         scatter_body<float>((const float*)pos, i, cursor, pts4, pid);
    }
}

// ---------------------------------------------------------------------------
// KNN (converged; unchanged): 128-thread blocks, SAT probe, hybrid
// staged/direct window scan, u64-key bitonic merge.
// ---------------------------------------------------------------------------
__device__ __forceinline__ int sat_at(const int* __restrict__ sat, int x, int y, int z) {
    if (x < 0 || y < 0 || z < 0) return 0;
    return sat[(z * GRID_R + y) * GRID_R + x];
}

__device__ __forceinline__ int boxcount(const int* __restrict__ sat,
                                        int x0, int x1, int y0, int y1, int z0, int z1) {
    return sat_at(sat, x1, y1, z1) - sat_at(sat, x0 - 1, y1, z1)
         - sat_at(sat, x1, y0 - 1, z1) - sat_at(sat, x1, y1, z0 - 1)
         + sat_at(sat, x0 - 1, y0 - 1, z1) + sat_at(sat, x0 - 1, y1, z0 - 1)
         + sat_at(sat, x1, y0 - 1, z0 - 1) - sat_at(sat, x0 - 1, y0 - 1, z0 - 1);
}

template <typename T>
__device__ void knn_body(const T* __restrict__ pos,
                         const int* __restrict__ cstart, const int* __restrict__ sat,
                         const float4* __restrict__ pts4, const int* __restrict__ pid,
                         int* __restrict__ idx_out,
                         int* __restrict__ rs, int* __restrict__ epf) {
    const int tid  = threadIdx.x;
    const int lane = tid & 31;
    const int i    = blockIdx.x * 4 + (tid >> 5);

    const float pix = ldf(pos, 3 * i + 0);
    const float piy = ldf(pos, 3 * i + 1);
    const float piz = ldf(pos, 3 * i + 2);
    const float sqi = fmaf(pix, pix, fmaf(piy, piy, piz * piz));
    const int cx = cell_of(pix), cy = cell_of(piy), cz = cell_of(piz);

    unsigned long long bk[KNN];
#pragma unroll
    for (int q = 0; q < KNN; ++q) bk[q] = SENT_KEY;
    unsigned long long tk = SENT_KEY;

    auto do_insert = [&](unsigned long long ck) {
#pragma unroll
        for (int q = 0; q < KNN; ++q) {
            const unsigned long long old = bk[q];
            const bool ins = ck < old;
            bk[q] = ins ? ck : old;
            ck    = ins ? old : ck;
        }
        tk = (bk[KNN - 1] < tk) ? bk[KNN - 1] : tk;
    };

    auto clip_row = [&](int ycell, int zcell, float clip2, bool doclip,
                        int x0, int x1, int& cxa, int& cxb) -> bool {
        cxa = x0; cxb = x1;
        if (doclip) {
            const float ylo = GLO + (float)ycell * CELL_E;
            const float zlo = GLO + (float)zcell * CELL_E;
            const float dy = fmaxf(0.0f, fmaxf(ylo - piy, piy - (ylo + CELL_E)));
            const float dz = fmaxf(0.0f, fmaxf(zlo - piz, piz - (zlo + CELL_E)));
            const float rad2 = clip2 - dy * dy - dz * dz;
            if (rad2 <= 0.0f) return false;
            const float hr = sqrtf(rad2) + 1e-4f;
            cxa = max(x0, (int)floorf((pix - hr - GLO) * CELL_INV));
            cxb = min(x1, (int)floorf((pix + hr - GLO) * CELL_INV));
        }
        return cxa <= cxb;
    };

    auto cand_key = [&](int si) -> unsigned long long {
        const float4 cq = pts4[si];
        const int pj = pid[si];
        const float d = fmaf(cq.x, pix, fmaf(cq.y, piy, fmaf(cq.z, piz, cq.w)));
        if (pj == i) return SENT_KEY;
        return ((unsigned long long)fkey(d) << 32) | (unsigned)pj;
    };

    auto scan_win = [&](int rr, float clipR) {
        const int x0 = max(cx - rr, 0), x1 = min(cx + rr, GRID_R - 1);
        const int y0 = max(cy - rr, 0), y1 = min(cy + rr, GRID_R - 1);
        const int z0 = max(cz - rr, 0), z1 = min(cz + rr, GRID_R - 1);
        const int ny = y1 - y0 + 1;
        const int nz = z1 - z0 + 1;
        const int R  = ny * nz;
        const float clip2 = clipR * clipR;
        const bool doclip = (clipR < 1e30f);

        if (R > R_DIRECT) {
            for (int t0 = lane; t0 < R; t0 += 128) {
                int s0v[4], s1v[4];
#pragma unroll
                for (int k = 0; k < 4; ++k) {
                    const int row = t0 + (k << 5);
                    s0v[k] = 0; s1v[k] = 0;
                    if (row < R) {
                        const int iz = row / ny;
                        const int iy = row - iz * ny;
                        int cxa, cxb;
                        if (clip_row(y0 + iy, z0 + iz, clip2, doclip, x0, x1, cxa, cxb)) {
                            const int c0 = ((z0 + iz) * GRID_R + (y0 + iy)) * GRID_R + cxa;
                            s0v[k] = cstart[c0];
                            s1v[k] = cstart[c0 + (cxb - cxa) + 1];
                        }
                    }
                }
#pragma unroll
                for (int k = 0; k < 4; ++k) {
                    for (int si = s0v[k]; si < s1v[k]; ++si) {
                        const unsigned long long ck = cand_key(si);
                        if (ck <= tk) do_insert(ck);
                    }
                }
            }
            return;
        }

        for (int cb = 0; cb < R; cb += 32) {
            const int lr = cb + lane;
            int cnt_r = 0, st_r = 0;
            if (lr < R) {
                const int izq = lr / ny;
                const int iyq = lr - izq * ny;
                int cxa, cxb;
                if (clip_row(y0 + iyq, z0 + izq, clip2, doclip, x0, x1, cxa, cxb)) {
                    const int c0 = ((z0 + izq) * GRID_R + (y0 + iyq)) * GRID_R + cxa;
                    st_r  = cstart[c0];
                    cnt_r = cstart[c0 + (cxb - cxa) + 1] - st_r;
                }
            }
            int pv = cnt_r;
#pragma unroll
            for (int s = 1; s < 32; s <<= 1) {
                const int u = __shfl_up(pv, s, 32);
                if (lane >= s) pv += u;
            }
            const int Mtot = __shfl(pv, 31, 32);
            asm volatile("s_waitcnt lgkmcnt(0)" ::: "memory");
            rs[lane]  = st_r;
            epf[lane] = (lr < R) ? (pv - cnt_r) : 0x7fffffff;
            asm volatile("s_waitcnt lgkmcnt(0)" ::: "memory");
            for (int tb = 0; tb < Mtot; tb += 128) {
                unsigned long long ck[4];
#pragma unroll
                for (int k = 0; k < 4; ++k) {
                    const int t = tb + (k << 5) + lane;
                    ck[k] = SENT_KEY;
                    if (t < Mtot) {
                        int p = 0;
#pragma unroll
                        for (int st = 16; st >= 1; st >>= 1)
                            if (epf[p + st] <= t) p += st;
                        ck[k] = cand_key(rs[p] + (t - epf[p]));
                    }
                }
#pragma unroll
                for (int k = 0; k < 4; ++k)
                    if (ck[k] <= tk) do_insert(ck[k]);
            }
        }
    };

    auto merge_all = [&]() {
#pragma unroll
        for (int s = 1; s < 32; s <<= 1) {
            unsigned long long m[KNN];
#pragma unroll
            for (int q = 0; q < KNN; ++q) {
                const unsigned long long o = __shfl_xor(bk[KNN - 1 - q], s, 32);
                m[q] = (bk[q] < o) ? bk[q] : o;
            }
#pragma unroll
            for (int d = 4; d >= 1; d >>= 1) {
#pragma unroll
                for (int q = 0; q < KNN; ++q) {
                    if (!(q & d)) {
                        const unsigned long long a = m[q], b = m[q + d];
                        const bool sw = b < a;
                        m[q]     = sw ? b : a;
                        m[q + d] = sw ? a : b;
                    }
                }
            }
#pragma unroll
            for (int q = 0; q < KNN; ++q) bk[q] = m[q];
        }
        tk = bk[KNN - 1];
    };

    int r;
    {
        const int rl = lane + 1;
        const int bx0 = max(cx - rl, 0), bx1 = min(cx + rl, GRID_R - 1);
        const int by0 = max(cy - rl, 0), by1 = min(cy + rl, GRID_R - 1);
        const int bz0 = max(cz - rl, 0), bz1 = min(cz + rl, GRID_R - 1);
        const int cntl = boxcount(sat, bx0, bx1, by0, by1, bz0, bz1);
        const unsigned long long m9  = __ballot(cntl >= NBR_LO);
        const unsigned long long m26 = __ballot(cntl >= NBR_MIN);
        const unsigned sh  = (unsigned)(tid & 32);
        const unsigned mh9  = (unsigned)(m9  >> sh);
        const unsigned mh26 = (unsigned)(m26 >> sh);
        const int r9  = mh9  ? (int)__ffs(mh9)  : 32;
        const int r26 = mh26 ? (int)__ffs(mh26) : 32;
        const int cnt26 = __shfl(cntl, r26 - 1, 32);
        r = (cnt26 <= M_CAP) ? r26 : r9;
    }

    scan_win(r, INFINITY);

    {
        float mg = INFINITY;
        bool full = true;
        if (cx - r > 0)          { mg = fminf(mg, pix - (GLO + (float)(cx - r) * CELL_E));     full = false; }
        if (cx + r < GRID_R - 1) { mg = fminf(mg, (GLO + (float)(cx + r + 1) * CELL_E) - pix); full = false; }
        if (cy - r > 0)          { mg = fminf(mg, piy - (GLO + (float)(cy - r) * CELL_E));     full = false; }
        if (cy + r < GRID_R - 1) { mg = fminf(mg, (GLO + (float)(cy + r + 1) * CELL_E) - piy); full = false; }
        if (cz - r > 0)          { mg = fminf(mg, piz - (GLO + (float)(cz - r) * CELL_E));     full = false; }
        if (cz + r < GRID_R - 1) { mg = fminf(mg, (GLO + (float)(cz + r + 1) * CELL_E) - piz); full = false; }

        merge_all();
        bool done = full;
        const unsigned long long d8key = bk[KNN - 1];
        const float d8 = fkey_inv((unsigned)(d8key >> 32));
        if (!full) {
            const float mge  = mg - 1e-5f;
            const float need = mge * mge - sqi;
            done = (d8 < need);
        }

        if (!done) {
            float s2 = sqrtf(fmaxf(d8 + sqi, 0.0f)) + 1e-4f;
            s2 = fminf(s2, 9.0f);
            auto dneed = [&](float frac, int clip) -> int {
                int nd = (int)ceilf((s2 - frac) * CELL_INV);
                nd = max(nd, 0);
                return min(nd, clip);
            };
            const float fxm = pix - (GLO + (float)cx * CELL_E);
            const float fxp = (GLO + (float)(cx + 1) * CELL_E) - pix;
            const float fym = piy - (GLO + (float)cy * CELL_E);
            const float fyp = (GLO + (float)(cy + 1) * CELL_E) - piy;
            const float fzm = piz - (GLO + (float)cz * CELL_E);
            const float fzp = (GLO + (float)(cz + 1) * CELL_E) - piz;
            int r2 = r + 1;
            r2 = max(r2, dneed(fxm, cx));
            r2 = max(r2, dneed(fxp, GRID_R - 1 - cx));
            r2 = max(r2, dneed(fym, cy));
            r2 = max(r2, dneed(fyp, GRID_R - 1 - cy));
            r2 = max(r2, dneed(fzm, cz));
            r2 = max(r2, dneed(fzp, GRID_R - 1 - cz));
            r2 = min(r2, GRID_R);

#pragma unroll
            for (int q = 0; q < KNN; ++q) bk[q] = SENT_KEY;
            tk = d8key;
            scan_win(r2, (d8 < INFINITY) ? s2 : INFINITY);
            merge_all();
        }
    }

    if (lane == 0) {
#pragma unroll
        for (int k = 0; k < KNN; ++k) idx_out[i * 9 + k] = clamp_idx((int)(unsigned)bk[k]);
        idx_out[i * 9 + 8] = i;
    }
}

__global__ __launch_bounds__(128) void knn_grid_kernel(const void* __restrict__ pos,
                                                       const int* __restrict__ flag,
                                                       const int* __restrict__ cstart,
                                                       const int* __restrict__ sat,
                                                       const float4* __restrict__ pts4,
                                                       const int* __restrict__ pid,
                                                       int* __restrict__ idx_out) {
    __shared__ int rs[4][32];
    __shared__ int epf[4][32];
    const int sg = threadIdx.x >> 5;
    if (get_dt(flag) == DT_BF16)
        knn_body<__hip_bfloat16>((const __hip_bfloat16*)pos, cstart, sat, pts4, pid, idx_out,
                                 rs[sg], epf[sg]);
    else
        knn_body<float>((const float*)pos, cstart, sat, pts4, pid, idx_out, rs[sg], epf[sg]);
}

// ---------------------------------------------------------------------------
// conv1+zw FUSED v2: 8 targets/block (grid 2048). Same shared-weight-register
// transform that won on conv2 (r16: 53->49): each thread computes targets tl
// and tl+4 with one set of staged weights -> per-target staging cost (wB 2048
// + W2a 4288 elements/block) halved. LDS big[] = 4352 floats covers phase A
// (wB[0..2047] + h1s[2048..4351]) and phase B (W2a overlay, 4288).
// Arithmetic per target identical to v1.
// ---------------------------------------------------------------------------
struct Conv1Smem {
    alignas(16) float big[4352];
    alignas(16) float wsum[3 * 32];
    alignas(16) float wbot[3 * 32];
    alignas(16) float posn[8][9][3];
    alignas(16) float xr[8][64];
    float bA[32];
    float bB[64];
    float bA2[64];
};

template <typename T>
__device__ void conv1_body(const T* __restrict__ pos, const int* __restrict__ idx,
                           const T* __restrict__ W1a, const T* __restrict__ b1a,
                           const T* __restrict__ W1b, const T* __restrict__ b1b,
                           const T* __restrict__ W2a, const T* __restrict__ b2a,
                           float* __restrict__ x1, Conv1Smem& s) {
    const int tid = threadIdx.x;
    float* wB  = s.big;
    float* h1s = s.big + 2048;

    for (int e = tid; e < 96; e += 256) {
        const float bot = ldf(W1a, 96 + e);
        s.wsum[e] = ldf(W1a, e) + bot;
        s.wbot[e] = bot;
    }
    if (tid < 32) s.bA[tid] = ldf(b1a, tid);
    for (int e = tid; e < 2048; e += 256) wB[e] = ldf(W1b, e);
    if (tid < 64) s.bB[tid] = ldf(b1b, tid);
    if (tid < 64) s.bA2[tid] = ldf(b2a, tid);

    const int tl   = tid >> 6;         // slot A (0..3); slot B = tl+4
    const int lane = tid & 63;
    const int iA   = blockIdx.x * 8 + tl;
    const int iB   = iA + 4;

    if (lane < 27) {
        const int n = lane / 3, c = lane % 3;
        const int jA = clamp_idx(idx[iA * 9 + n]);
        const int jB = clamp_idx(idx[iB * 9 + n]);
        s.posn[tl][n][c]     = ldf(pos, 3 * jA + c);
        s.posn[tl + 4][n][c] = ldf(pos, 3 * jB + c);
    }
    const float pA0 = ldf(pos, 3 * iA + 0);
    const float pA1 = ldf(pos, 3 * iA + 1);
    const float pA2 = ldf(pos, 3 * iA + 2);
    const float pB0 = ldf(pos, 3 * iB + 0);
    const float pB1 = ldf(pos, 3 * iB + 1);
    const float pB2 = ldf(pos, 3 * iB + 2);
    __syncthreads();

    for (int e = lane; e < 288; e += 64) {
        const int n = e >> 5, k = e & 31;
        const float ws0 = s.wsum[k], ws1 = s.wsum[32 + k], ws2 = s.wsum[64 + k];
        const float wb0 = s.wbot[k], wb1 = s.wbot[32 + k], wb2 = s.wbot[64 + k];
        const float bAk = s.bA[k];
        {
            float b = fmaf(pA0, wb0, fmaf(pA1, wb1, pA2 * wb2));
            float v = bAk - b;
            v = fmaf(s.posn[tl][n][0], ws0, v);
            v = fmaf(s.posn[tl][n][1], ws1, v);
            v = fmaf(s.posn[tl][n][2], ws2, v);
            h1s[tl * 288 + n * 32 + k] = fmaxf(v, 0.0f);
        }
        {
            float b = fmaf(pB0, wb0, fmaf(pB1, wb1, pB2 * wb2));
            float v = bAk - b;
            v = fmaf(s.posn[tl + 4][n][0], ws0, v);
            v = fmaf(s.posn[tl + 4][n][1], ws1, v);
            v = fmaf(s.posn[tl + 4][n][2], ws2, v);
            h1s[(tl + 4) * 288 + n * 32 + k] = fmaxf(v, 0.0f);
        }
    }
    __syncthreads();

    float accA[9], accB[9];
#pragma unroll
    for (int n = 0; n < 9; ++n) { accA[n] = 0.0f; accB[n] = 0.0f; }
#pragma unroll
    for (int kt = 0; kt < 32; kt += 8) {
        float w0 = wB[(kt + 0) * 64 + lane];
        float w1 = wB[(kt + 1) * 64 + lane];
        float w2 = wB[(kt + 2) * 64 + lane];
        float w3 = wB[(kt + 3) * 64 + lane];
        float w4 = wB[(kt + 4) * 64 + lane];
        float w5 = wB[(kt + 5) * 64 + lane];
        float w6 = wB[(kt + 6) * 64 + lane];
        float w7 = wB[(kt + 7) * 64 + lane];
#pragma unroll
        for (int n = 0; n < 9; ++n) {
            const float4 ha = *(const float4*)&h1s[tl * 288 + n * 32 + kt];
            const float4 hb = *(const float4*)&h1s[tl * 288 + n * 32 + kt + 4];
            const float4 hc = *(const float4*)&h1s[(tl + 4) * 288 + n * 32 + kt];
            const float4 hd = *(const float4*)&h1s[(tl + 4) * 288 + n * 32 + kt + 4];
            float a = accA[n], b = accB[n];
            a = fmaf(ha.x, w0, a); a = fmaf(ha.y, w1, a);
            a = fmaf(ha.z, w2, a); a = fmaf(ha.w, w3, a);
            a = fmaf(hb.x, w4, a); a = fmaf(hb.y, w5, a);
            a = fmaf(hb.z, w6, a); a = fmaf(hb.w, w7, a);
            b = fmaf(hc.x, w0, b); b = fmaf(hc.y, w1, b);
            b = fmaf(hc.z, w2, b); b = fmaf(hc.w, w3, b);
            b = fmaf(hd.x, w4, b); b = fmaf(hd.y, w5, b);
            b = fmaf(hd.z, w6, b); b = fmaf(hd.w, w7, b);
            accA[n] = a; accB[n] = b;
        }
    }
    float mA = accA[0], mB = accB[0];
#pragma unroll
    for (int n = 1; n < 9; ++n) { mA = fmaxf(mA, accA[n]); mB = fmaxf(mB, accB[n]); }
    const float xvA = fmaxf(mA + s.bB[lane], 0.0f);
    const float xvB = fmaxf(mB + s.bB[lane], 0.0f);

    __syncthreads();                    // all reads of wB/h1s complete
    s.xr[tl][lane]     = xvA;
    s.xr[tl + 4][lane] = xvB;
    for (int e = tid; e < 4288; e += 256) s.big[e] = ldf(W2a, e);   // overlay W2a
    __syncthreads();

    // zw epilogue for both targets
    {
        float a0 = s.bA2[lane], a1 = 0.0f, a2 = 0.0f, a3 = 0.0f;
        float b0 = s.bA2[lane], b1 = 0.0f, b2 = 0.0f, b3 = 0.0f;
#pragma unroll
        for (int c = 0; c < 64; c += 4) {
            const float wc0 = s.big[(c + 0) * 64 + lane];
            const float wc1 = s.big[(c + 1) * 64 + lane];
            const float wc2 = s.big[(c + 2) * 64 + lane];
            const float wc3 = s.big[(c + 3) * 64 + lane];
            a0 = fmaf(s.xr[tl][c + 0], wc0, a0);
            a1 = fmaf(s.xr[tl][c + 1], wc1, a1);
            a2 = fmaf(s.xr[tl][c + 2], wc2, a2);
            a3 = fmaf(s.xr[tl][c + 3], wc3, a3);
            b0 = fmaf(s.xr[tl + 4][c + 0], wc0, b0);
            b1 = fmaf(s.xr[tl + 4][c + 1], wc1, b1);
            b2 = fmaf(s.xr[tl + 4][c + 2], wc2, b2);
            b3 = fmaf(s.xr[tl + 4][c + 3], wc3, b3);
        }
        const float wx = s.big[64 * 64 + lane];
        const float wy = s.big[65 * 64 + lane];
        const float wz = s.big[66 * 64 + lane];
        float a = (a0 + a1) + (a2 + a3);
        a = fmaf(pA0, wx, a);
        a = fmaf(pA1, wy, a);
        a = fmaf(pA2, wz, a);
        x1[iA * 64 + lane] = a;
        float b = (b0 + b1) + (b2 + b3);
        b = fmaf(pB0, wx, b);
        b = fmaf(pB1, wy, b);
        b = fmaf(pB2, wz, b);
        x1[iB * 64 + lane] = b;
    }
}

__global__ __launch_bounds__(256) void conv1zw_kernel(const void* __restrict__ pos,
                                                      const int* __restrict__ flag,
                                                      const int* __restrict__ idx,
                                                      const void* __restrict__ W1a,
                                                      const void* __restrict__ b1a,
                                                      const void* __restrict__ W1b,
                                                      const void* __restrict__ b1b,
                                                      const void* __restrict__ W2a,
                                                      const void* __restrict__ b2a,
                                                      float* __restrict__ x1) {
    __shared__ Conv1Smem s;
    if (get_dt(flag) == DT_BF16)
        conv1_body<__hip_bfloat16>((const __hip_bfloat16*)pos, idx,
            (const __hip_bfloat16*)W1a, (const __hip_bfloat16*)b1a,
            (const __hip_bfloat16*)W1b, (const __hip_bfloat16*)b1b,
            (const __hip_bfloat16*)W2a, (const __hip_bfloat16*)b2a, x1, s);
    else
        conv1_body<float>((const float*)pos, idx, (const float*)W1a, (const float*)b1a,
            (const float*)W1b, (const float*)b1b,
            (const float*)W2a, (const float*)b2a, x1, s);
}

// ---------------------------------------------------------------------------
// conv2+head v12 (unchanged from r16): 8 targets/block, shared weight regs.
// ---------------------------------------------------------------------------
struct Conv2Smem {
    alignas(16) float h1s[8][9 * 64];
    alignas(16) float row[8][128];
    alignas(16) float wbot[3 * 64];
    alignas(16) float wc[640];
    float bcs[5];
    float sv[8][5];
    int   nb[8][9];
};

template <typename T>
__device__ void conv2_body(const T* __restrict__ pos, const int* __restrict__ idx,
                           const float* __restrict__ zw,
                           const T* __restrict__ W2a, const T* __restrict__ W2b,
                           const T* __restrict__ b2b, const T* __restrict__ Wc,
                           const T* __restrict__ bc, T* __restrict__ out, Conv2Smem& s) {
    const int tid  = threadIdx.x;
    const int tl   = tid >> 6;
    const int lane = tid & 63;
    const int iA   = blockIdx.x * 8 + tl;
    const int iB   = iA + 4;

    for (int e = tid; e < 192; e += 256) s.wbot[e] = ldf(W2a, 4096 + e);
    for (int e = tid; e < 640; e += 256) s.wc[e] = ldf(Wc, e);
    if (tid < 5) s.bcs[tid] = ldf(bc, tid);

    if (lane < 9) {
        s.nb[tl][lane]     = clamp_idx(idx[iA * 9 + lane]);
        s.nb[tl + 4][lane] = clamp_idx(idx[iB * 9 + lane]);
    }
    const float pA0 = ldf(pos, 3 * iA + 0);
    const float pA1 = ldf(pos, 3 * iA + 1);
    const float pA2 = ldf(pos, 3 * iA + 2);
    const float pB0 = ldf(pos, 3 * iB + 0);
    const float pB1 = ldf(pos, 3 * iB + 1);
    const float pB2 = ldf(pos, 3 * iB + 2);
    __syncthreads();

    {
        const float wb0 = s.wbot[lane], wb1 = s.wbot[64 + lane], wb2 = s.wbot[128 + lane];
        const float viA = fmaf(pA0, wb0, fmaf(pA1, wb1, pA2 * wb2));
        const float viB = fmaf(pB0, wb0, fmaf(pB1, wb1, pB2 * wb2));
#pragma unroll
        for (int n = 0; n < 9; ++n) {
            const int jA = s.nb[tl][n];
            const int jB = s.nb[tl + 4][n];
            s.h1s[tl][n * 64 + lane]     = fmaxf(zw[jA * 64 + lane] - viA, 0.0f);
            s.h1s[tl + 4][n * 64 + lane] = fmaxf(zw[jB * 64 + lane] - viB, 0.0f);
        }
    }
    __syncthreads();

    float aA0[9], aA1[9], aB0[9], aB1[9];
#pragma unroll
    for (int n = 0; n < 9; ++n) { aA0[n] = 0.0f; aA1[n] = 0.0f; aB0[n] = 0.0f; aB1[n] = 0.0f; }
#pragma unroll
    for (int kt = 0; kt < 64; kt += 4) {
        const float wa0 = ldf(W2b, (kt + 0) * 128 + lane);
        const float wa1 = ldf(W2b, (kt + 1) * 128 + lane);
        const float wa2 = ldf(W2b, (kt + 2) * 128 + lane);
        const float wa3 = ldf(W2b, (kt + 3) * 128 + lane);
        const float wb0 = ldf(W2b, (kt + 0) * 128 + lane + 64);
        const float wb1 = ldf(W2b, (kt + 1) * 128 + lane + 64);
        const float wb2 = ldf(W2b, (kt + 2) * 128 + lane + 64);
        const float wb3 = ldf(W2b, (kt + 3) * 128 + lane + 64);
#pragma unroll
        for (int n = 0; n < 9; ++n) {
            const float4 hA = *(const float4*)&s.h1s[tl][n * 64 + kt];
            const float4 hB = *(const float4*)&s.h1s[tl + 4][n * 64 + kt];
            float x0 = aA0[n], x1v = aA1[n], y0 = aB0[n], y1 = aB1[n];
            x0 = fmaf(hA.x, wa0, x0); x0 = fmaf(hA.y, wa1, x0);
            x0 = fmaf(hA.z, wa2, x0); x0 = fmaf(hA.w, wa3, x0);
            x1v = fmaf(hA.x, wb0, x1v); x1v = fmaf(hA.y, wb1, x1v);
            x1v = fmaf(hA.z, wb2, x1v); x1v = fmaf(hA.w, wb3, x1v);
            y0 = fmaf(hB.x, wa0, y0); y0 = fmaf(hB.y, wa1, y0);
            y0 = fmaf(hB.z, wa2, y0); y0 = fmaf(hB.w, wa3, y0);
            y1 = fmaf(hB.x, wb0, y1); y1 = fmaf(hB.y, wb1, y1);
            y1 = fmaf(hB.z, wb2, y1); y1 = fmaf(hB.w, wb3, y1);
            aA0[n] = x0; aA1[n] = x1v; aB0[n] = y0; aB1[n] = y1;
        }
    }
    float mA0 = aA0[0], mA1 = aA1[0], mB0 = aB0[0], mB1 = aB1[0];
#pragma unroll
    for (int n = 1; n < 9; ++n) {
        mA0 = fmaxf(mA0, aA0[n]); mA1 = fmaxf(mA1, aA1[n]);
        mB0 = fmaxf(mB0, aB0[n]); mB1 = fmaxf(mB1, aB1[n]);
    }
    const float b0 = ldf(b2b, lane), b1 = ldf(b2b, lane + 64);
    s.row[tl][lane]          = fmaxf(mA0 + b0, 0.0f);
    s.row[tl][lane + 64]     = fmaxf(mA1 + b1, 0.0f);
    s.row[tl + 4][lane]      = fmaxf(mB0 + b0, 0.0f);
    s.row[tl + 4][lane + 64] = fmaxf(mB1 + b1, 0.0f);
    __syncthreads();

    if (tid < 40) {
        const int tgt = tid / 5, o = tid % 5;
        float v = s.bcs[o];
        for (int k = 0; k < 128; ++k) v = fmaf(s.row[tgt][k], s.wc[k * 5 + o], v);
        s.sv[tgt][o] = v;
    }
    __syncthreads();
    if (tid < 40) {
        const int tgt = tid / 5, o = tid % 5;
        float m = s.sv[tgt][0];
#pragma unroll
        for (int q = 1; q < 5; ++q) m = fmaxf(m, s.sv[tgt][q]);
        float sum = 0.0f;
#pragma unroll
        for (int q = 0; q < 5; ++q) sum += expf(s.sv[tgt][q] - m);
        const float lse = m + logf(sum);
        stf(out, (blockIdx.x * 8 + tgt) * 5 + o, s.sv[tgt][o] - lse);
    }
}

__global__ __launch_bounds__(256) void conv2_head_kernel(const void* __restrict__ pos,
                                                         const int* __restrict__ flag,
                                                         const int* __restrict__ idx,
                                                         const float* __restrict__ zw,
                                                         const void* __restrict__ W2a,
                                                         const void* __restrict__ W2b,
                                                         const void* __restrict__ b2b,
                                                         const void* __restrict__ Wc,
                                                         const void* __restrict__ bc,
                                                         void* __restrict__ out) {
    __shared__ Conv2Smem s;
    if (get_dt(flag) == DT_BF16)
        conv2_body<__hip_bfloat16>((const __hip_bfloat16*)pos, idx, zw,
            (const __hip_bfloat16*)W2a, (const __hip_bfloat16*)W2b, (const __hip_bfloat16*)b2b,
            (const __hip_bfloat16*)Wc, (const __hip_bfloat16*)bc, (__hip_bfloat16*)out, s);
    else
        conv2_body<float>((const float*)pos, idx, zw, (const float*)W2a, (const float*)W2b,
            (const float*)b2b, (const float*)Wc, (const float*)bc, (float*)out, s);
}

// ---------------------------------------------------------------------------
extern "C" void kernel_launch(void* const* d_in, const int* in_sizes, int n_in,
                              void* d_out, int out_size, void* d_ws, size_t ws_size,
                              hipStream_t stream) {
    if (ws_size < (size_t)WS_NEEDED) return;

    char* ws = (char*)d_ws;
    int*    flag     = (int*)(ws + WS_FLAG_OFF);
    int*    idx      = (int*)(ws + WS_IDX_OFF);
    float*  x1       = (float*)(ws + WS_X1_OFF);
    int*    sat      = (int*)(ws + WS_SAT_OFF);
    int*    cstart   = (int*)(ws + WS_START_OFF);
    int*    cursor   = (int*)(ws + WS_CURSOR_OFF);
    int*    pid      = (int*)(ws + WS_PID_OFF);
    float4* pts4     = (float4*)(ws + WS_PTS_OFF);
    int*    rowtot   = (int*)(ws + WS_ROWTOT_OFF);
    int*    rowstart = (int*)(ws + WS_ROWSTART_OFF);
    int*    xpre     = (int*)(ws + WS_XPRE_OFF);

    zero_kernel<<<NCELLS / 256, 256, 0, stream>>>(sat, flag);
    sniff_kernel<<<64, 256, 0, stream>>>((const unsigned short*)d_in[0], flag);
    grid_count_kernel<<<N_PTS / 256, 256, 0, stream>>>(d_in[0], flag, sat);
    rowscan_kernel<<<NROWS2D / 256, 256, 0, stream>>>(sat, xpre, rowtot);
    rowoffset_kernel<<<1, 256, 0, stream>>>(rowtot, rowstart);
    cellsaty_kernel<<<NROWS2D / 256, 256, 0, stream>>>(xpre, rowstart, cstart, cursor, sat);
    satzscatter_kernel<<<9 + N_PTS / 256, 256, 0, stream>>>(d_in[0], flag, sat, cursor, pts4, pid);
    knn_grid_kernel<<<N_PTS / 4, 128, 0, stream>>>(d_in[0], flag, cstart, sat, pts4, pid, idx);
    conv1zw_kernel<<<N_PTS / 8, 256, 0, stream>>>(d_in[0], flag, idx,
        d_in[1], d_in[2], d_in[3], d_in[4], d_in[5], d_in[6], x1);
    conv2_head_kernel<<<N_PTS / 8, 256, 0, stream>>>(d_in[0], flag, idx, x1,
        d_in[5], d_in[7], d_in[8], d_in[9], d_in[10], d_out);
}